// Round 7
// baseline (175.374 us; speedup 1.0000x reference)
//
#include <hip/hip_runtime.h>
#include <math.h>

// GptOssRouter: T=16384, H=2880, E=128, K=4.
// K1: bf16 MFMA GEMM (x@W^T+bias) over 1024 blocks (32tok x 64exp each),
//     double-buffered LDS, 1 barrier/chunk, reg-prefetch issue-early.
//     Raw fp32 logits written into the output score rows (scratch).
// K2: per token: PARALLEL rank-based top-8 (no serial shuffle chain), fp64
//     re-accumulation of the 8 candidates (x pre-converted to fp64 in LDS,
//     permuted layout for conflict-free ds_read_b128), parallel rank-based
//     top-4 sort + parallel fp64 softmax; overwrite row + idx output.

#define T_TOK 16384
#define HDIM  2880
#define EEXP  128
#define KTOP  4

// ---------------- Kernel 1 ----------------
#define TM    32            // tokens per block
#define EN    64            // experts per block
#define NT1   256           // 4 waves
#define KC    64            // K-chunk (2880 = 45*64)
#define NC4   (KC / 4)      // 16 float4 per row-chunk
#define NCH   (HDIM / KC)   // 45
#define LDROW 144           // bf16 LDS row stride in BYTES (64 bf16 = 128B + 16 pad)
#define ROWS  (TM + EN)     // 96 rows per buffer (32 x + 64 w)
#define BUFB  (ROWS * LDROW)// 13824 B per buffer
#define NPF   6             // float4 staged per thread per chunk (96*16/256)

typedef __attribute__((ext_vector_type(8))) short bf16x8;
typedef __attribute__((ext_vector_type(4))) float f32x4;

// pack trunc-bf16(a), trunc-bf16(b) into one u32 (a in low half) via v_perm
static __device__ __forceinline__ unsigned pack2bf(float a, float b) {
    union { float f; unsigned u; } ua, ub; ua.f = a; ub.f = b;
    return __builtin_amdgcn_perm(ub.u, ua.u, 0x07060302u);
}

__global__ __launch_bounds__(NT1, 4) void router_gemm(
    const float* __restrict__ x, const float* __restrict__ w,
    const float* __restrict__ bias, float* __restrict__ out)
{
    __shared__ char smem[2 * BUFB];     // 27648 B
    const int tid = threadIdx.x;
    const int blk = blockIdx.x;
    const int xcd = blk & 7;
    const int j   = blk >> 3;           // 0..127 within XCD
    const int be  = j & 1;              // expert half
    const int p   = xcd * 64 + (j >> 1);// token tile 0..511
    const int tok0 = p * TM;
    const int e0   = be * EN;

    const int lane = tid & 63;
    const int wv   = tid >> 6;
    const int wt   = wv & 1;            // token 16-row group
    const int wn   = wv >> 1;           // expert 32-col group
    const int r    = lane & 15;
    const int g    = lane >> 4;

    // staging map: 96 rows x 16 float4 = 1536 float4, 6 per thread
    const float* sptr[NPF];
    int soff[NPF];
#pragma unroll
    for (int i = 0; i < NPF; ++i) {
        int f = tid + i * NT1;
        int row = f >> 4, c4 = f & 15;
        soff[i] = row * LDROW + c4 * 8;
        sptr[i] = (row < TM) ? (x + (size_t)(tok0 + row) * HDIM + c4 * 4)
                             : (w + (size_t)(e0 + row - TM) * HDIM + c4 * 4);
    }

    f32x4 acc[2];
    const f32x4 zf = {0.f, 0.f, 0.f, 0.f};
    acc[0] = zf; acc[1] = zf;

    float4 pf[NPF];
    // prologue: chunk 0 -> regs -> buf0
#pragma unroll
    for (int i = 0; i < NPF; ++i) pf[i] = *(const float4*)sptr[i];
#pragma unroll
    for (int i = 0; i < NPF; ++i) {
        uint2 c; c.x = pack2bf(pf[i].x, pf[i].y); c.y = pack2bf(pf[i].z, pf[i].w);
        *(uint2*)(smem + soff[i]) = c;
    }
    __syncthreads();

    for (int c = 0; c < NCH; ++c) {
        char* cb = smem + (c & 1) * BUFB;        // compute buffer
        char* sb = smem + ((c & 1) ^ 1) * BUFB;  // stage buffer
        const bool more = (c + 1 < NCH);
        if (more) {
            int koff = (c + 1) * KC;
#pragma unroll
            for (int i = 0; i < NPF; ++i)
                pf[i] = *(const float4*)(sptr[i] + koff);
        }
#pragma unroll
        for (int ks = 0; ks < KC / 32; ++ks) {
            bf16x8 af = *(const bf16x8*)(cb + (wt * 16 + r) * LDROW + ks * 64 + g * 16);
#pragma unroll
            for (int n = 0; n < 2; ++n) {
                bf16x8 bfr = *(const bf16x8*)(cb + (TM + wn * 32 + n * 16 + r) * LDROW + ks * 64 + g * 16);
                acc[n] = __builtin_amdgcn_mfma_f32_16x16x32_bf16(af, bfr, acc[n], 0, 0, 0);
            }
        }
        if (more) {
#pragma unroll
            for (int i = 0; i < NPF; ++i) {
                uint2 cv; cv.x = pack2bf(pf[i].x, pf[i].y); cv.y = pack2bf(pf[i].z, pf[i].w);
                *(uint2*)(sb + soff[i]) = cv;
            }
        }
        __syncthreads();
    }

    // epilogue: logits(+bias) -> out score rows (scratch for K2)
#pragma unroll
    for (int n = 0; n < 2; ++n) {
        int e = e0 + wn * 32 + n * 16 + r;
        float bv = bias[e];
#pragma unroll
        for (int q = 0; q < 4; ++q) {
            int m = wt * 16 + g * 4 + q;
            out[(size_t)(tok0 + m) * EEXP + e] = acc[n][q] + bv;
        }
    }
}

// ---------------- Kernel 2 ----------------
#define NT2 256
#define NF4 (HDIM / 4)      // 720 float4 per row

__global__ __launch_bounds__(NT2) void router_rescore(
    const float* __restrict__ x, const float* __restrict__ w,
    const float* __restrict__ bias, float* __restrict__ out)
{
    // x row in fp64, permuted: float4-index fi=(i,s), component k stored at
    // i*128 + (k>>1)*64 + s*2 + (k&1)  -> both dot-loop ds_read_b128 are
    // lane-consecutive 16B (conflict-free). i=fi>>5 in [0,22], s=fi&31.
    __shared__ double xl[23 * 128];     // 23552 B
    __shared__ int    ci[8];
    __shared__ double cv[8];
    __shared__ double srt_v[8];
    __shared__ int    srt_i[8];
    __shared__ double evs[4];
    __shared__ float  sr[EEXP];

    const int t   = blockIdx.x;
    const int tid = threadIdx.x;
    const float* lrow = out + (size_t)t * EEXP;

    // stage x row -> fp64 LDS (permuted); 720 float4, 3 loop trips
    const float4* xr4 = (const float4*)(x + (size_t)t * HDIM);
    for (int fi = tid; fi < NF4; fi += NT2) {
        float4 xv = xr4[fi];
        int i = fi >> 5, s = fi & 31;
        double2 lo; lo.x = (double)xv.x; lo.y = (double)xv.y;
        double2 hi; hi.x = (double)xv.z; hi.y = (double)xv.w;
        *(double2*)(xl + (i << 7) + (s << 1))      = lo;
        *(double2*)(xl + (i << 7) + 64 + (s << 1)) = hi;
    }

    // parallel rank-based top-8: thread e ranks logit e among all 128.
    // Strict total order via index tie-break -> ranks unique -> scatter.
    if (tid < EEXP) {
        float my = lrow[tid];
        int rank = 0;
#pragma unroll 8
        for (int j2 = 0; j2 < EEXP; j2 += 4) {
            float4 lv = *(const float4*)(lrow + j2);
            rank += (lv.x > my) || (lv.x == my && (j2 + 0) < tid);
            rank += (lv.y > my) || (lv.y == my && (j2 + 1) < tid);
            rank += (lv.z > my) || (lv.z == my && (j2 + 2) < tid);
            rank += (lv.w > my) || (lv.w == my && (j2 + 3) < tid);
        }
        if (rank < 8) ci[rank] = tid;
    }
    if (tid >= 128 && tid < 160) ((float4*)sr)[tid - 128] = make_float4(0.f, 0.f, 0.f, 0.f);
    __syncthreads();

    // 32 lanes per candidate: coalesced fp32 w reads (cvt), fp64 x from LDS.
    const int c  = tid >> 5;            // candidate 0..7
    const int s  = tid & 31;            // sub-lane
    const int ce = ci[c];
    const float4* wr4 = (const float4*)(w + (size_t)ce * HDIM);
    double ax = 0.0, ay = 0.0, az = 0.0, aw = 0.0;
#pragma unroll 4
    for (int i = 0; i < 22; ++i) {      // 22*32 = 704 float4
        float4 wv = wr4[s + i * 32];
        const double* xp = xl + (i << 7) + (s << 1);
        double2 x01 = *(const double2*)(xp);
        double2 x23 = *(const double2*)(xp + 64);
        ax = fma(x01.x, (double)wv.x, ax);
        ay = fma(x01.y, (double)wv.y, ay);
        az = fma(x23.x, (double)wv.z, az);
        aw = fma(x23.y, (double)wv.w, aw);
    }
    if (s < 16) {                       // tail: remaining 16 float4 (i=22)
        float4 wv = wr4[704 + s];
        const double* xp = xl + (22 << 7) + (s << 1);
        double2 x01 = *(const double2*)(xp);
        double2 x23 = *(const double2*)(xp + 64);
        ax = fma(x01.x, (double)wv.x, ax);
        ay = fma(x01.y, (double)wv.y, ay);
        az = fma(x23.x, (double)wv.z, az);
        aw = fma(x23.y, (double)wv.w, aw);
    }
    double acc = (ax + az) + (ay + aw);
#pragma unroll
    for (int off = 16; off > 0; off >>= 1)
        acc += __shfl_xor(acc, off);    // butterfly closed within 32-lane group
    if (s == 0) cv[c] = acc + (double)bias[ce];
    __syncthreads();

    // parallel rank among the 8 candidates (fp64, index tie-break)
    if (tid < 8) {
        double mv = cv[tid]; int mi = ci[tid];
        int rank = 0;
#pragma unroll
        for (int j2 = 0; j2 < 8; ++j2)
            rank += (cv[j2] > mv) || (cv[j2] == mv && ci[j2] < mi);
        srt_v[rank] = mv; srt_i[rank] = mi;
    }
    __syncthreads();
    if (tid < 4) evs[tid] = exp(srt_v[tid] - srt_v[0]);
    __syncthreads();
    if (tid < 4) {
        double ssum = evs[0] + evs[1] + evs[2] + evs[3];
        float* oidx = out + (size_t)T_TOK * EEXP;
        oidx[(size_t)t * KTOP + tid] = (float)srt_i[tid];
        sr[srt_i[tid]] = (float)(evs[tid] / ssum);
    }
    __syncthreads();

    float4* orow = (float4*)(out + (size_t)t * EEXP);
    if (tid < 32) orow[tid] = ((float4*)sr)[tid];
}

extern "C" void kernel_launch(void* const* d_in, const int* in_sizes, int n_in,
                              void* d_out, int out_size, void* d_ws, size_t ws_size,
                              hipStream_t stream) {
    const float* x    = (const float*)d_in[0];
    const float* w    = (const float*)d_in[1];
    const float* bias = (const float*)d_in[2];
    float* out        = (float*)d_out;

    hipLaunchKernelGGL(router_gemm, dim3((T_TOK / TM) * (EEXP / EN)), dim3(NT1),
                       0, stream, x, w, bias, out);
    hipLaunchKernelGGL(router_rescore, dim3(T_TOK), dim3(NT2), 0, stream,
                       x, w, bias, out);
}

// Round 8
// 136.885 us; speedup vs baseline: 1.2812x; 1.2812x over previous
//
#include <hip/hip_runtime.h>
#include <math.h>

// GptOssRouter: T=16384, H=2880, E=128, K=4.
// K1: split-bf16 3-pass MFMA GEMM: x,w each split as v = h + l (h=trunc_bf16(v),
//     l=trunc_bf16(v-h), both splits exact) -> logit = xh*wh + xh*wl + xl*wh,
//     per-element rel err <= 2^-16, logit err sigma ~1.3e-5. fp32 logits to out.
// K2: rank-based top-8 from logits; if all 4 order-relevant gaps > TAU=2.5e-4
//     the fp32 order provably equals the fp64 order -> softmax directly (no
//     x/w reads). Else (~tens of tokens) inline fp64 re-accumulation of the 8
//     candidates. Index flips vs the float64 numpy reference are fatal, hence
//     the certified-gap design.

#define T_TOK 16384
#define HDIM  2880
#define EEXP  128
#define KTOP  4

// ---------------- Kernel 1 ----------------
#define TM    32            // tokens per block
#define EN    64            // experts per block
#define NT1   256           // 4 waves
#define KC    32            // K-chunk floats (2880 = 90*32)
#define NCH   (HDIM / KC)   // 90
#define LDROW 144           // bytes: 64 h + 64 l + 16 pad
#define ROWS  (TM + EN)     // 96 rows
#define BUFB  (ROWS * LDROW)// 13824 per buffer
#define NPF   3             // float4 per thread per chunk (96*8/256)

typedef __attribute__((ext_vector_type(8))) short bf16x8;
typedef __attribute__((ext_vector_type(4))) float f32x4;

// split v into h = trunc_bf16(v) (exact high part), l = trunc_bf16(v - h);
// writes 8B of h-words at base+off and 8B of l-words at base+off+64.
static __device__ __forceinline__ void split_write(char* base, int off, float4 v) {
    union { float4 v4; unsigned u[4]; } uv; uv.v4 = v;
    unsigned h01 = __builtin_amdgcn_perm(uv.u[1], uv.u[0], 0x07060302u);
    unsigned h23 = __builtin_amdgcn_perm(uv.u[3], uv.u[2], 0x07060302u);
    float r0 = v.x - __uint_as_float(uv.u[0] & 0xffff0000u);
    float r1 = v.y - __uint_as_float(uv.u[1] & 0xffff0000u);
    float r2 = v.z - __uint_as_float(uv.u[2] & 0xffff0000u);
    float r3 = v.w - __uint_as_float(uv.u[3] & 0xffff0000u);
    unsigned l01 = __builtin_amdgcn_perm(__float_as_uint(r1), __float_as_uint(r0), 0x07060302u);
    unsigned l23 = __builtin_amdgcn_perm(__float_as_uint(r3), __float_as_uint(r2), 0x07060302u);
    uint2 hw; hw.x = h01; hw.y = h23;
    uint2 lw; lw.x = l01; lw.y = l23;
    *(uint2*)(base + off)      = hw;
    *(uint2*)(base + off + 64) = lw;
}

__global__ __launch_bounds__(NT1, 4) void router_gemm(
    const float* __restrict__ x, const float* __restrict__ w,
    const float* __restrict__ bias, float* __restrict__ out)
{
    __shared__ char smem[2 * BUFB];     // 27648 B
    const int tid = threadIdx.x;
    const int blk = blockIdx.x;
    const int xcd = blk & 7;
    const int j   = blk >> 3;           // 0..127 within XCD
    const int be  = j & 1;              // expert half
    const int p   = xcd * 64 + (j >> 1);// token tile 0..511
    const int tok0 = p * TM;
    const int e0   = be * EN;

    const int lane = tid & 63;
    const int wv   = tid >> 6;
    const int wt   = wv & 1;            // token 16-row group
    const int wn   = wv >> 1;           // expert 32-col group
    const int r    = lane & 15;
    const int g    = lane >> 4;

    // staging map: 96 rows x 8 float4 = 768 float4, 3 per thread
    const float* sptr[NPF];
    int soff[NPF];
#pragma unroll
    for (int i = 0; i < NPF; ++i) {
        int f = tid + i * NT1;
        int row = f >> 3, c4 = f & 7;
        soff[i] = row * LDROW + c4 * 8;
        sptr[i] = (row < TM) ? (x + (size_t)(tok0 + row) * HDIM + c4 * 4)
                             : (w + (size_t)(e0 + row - TM) * HDIM + c4 * 4);
    }

    f32x4 acc[2];
    const f32x4 zf = {0.f, 0.f, 0.f, 0.f};
    acc[0] = zf; acc[1] = zf;

    float4 pf[NPF];
    // prologue: chunk 0 -> regs -> buf0
#pragma unroll
    for (int i = 0; i < NPF; ++i) pf[i] = *(const float4*)sptr[i];
#pragma unroll
    for (int i = 0; i < NPF; ++i) split_write(smem, soff[i], pf[i]);
    __syncthreads();

    for (int c = 0; c < NCH; ++c) {
        char* cb = smem + (c & 1) * BUFB;        // compute buffer
        char* sb = smem + ((c & 1) ^ 1) * BUFB;  // stage buffer
        const bool more = (c + 1 < NCH);
        if (more) {
            int koff = (c + 1) * KC;
#pragma unroll
            for (int i = 0; i < NPF; ++i)
                pf[i] = *(const float4*)(sptr[i] + koff);
        }
        {
            const int arow = (wt * 16 + r) * LDROW;
            bf16x8 ah = *(const bf16x8*)(cb + arow + g * 16);
            bf16x8 al = *(const bf16x8*)(cb + arow + 64 + g * 16);
#pragma unroll
            for (int n = 0; n < 2; ++n) {
                const int brow = (TM + wn * 32 + n * 16 + r) * LDROW;
                bf16x8 bh = *(const bf16x8*)(cb + brow + g * 16);
                bf16x8 bl = *(const bf16x8*)(cb + brow + 64 + g * 16);
                acc[n] = __builtin_amdgcn_mfma_f32_16x16x32_bf16(ah, bh, acc[n], 0, 0, 0);
                acc[n] = __builtin_amdgcn_mfma_f32_16x16x32_bf16(ah, bl, acc[n], 0, 0, 0);
                acc[n] = __builtin_amdgcn_mfma_f32_16x16x32_bf16(al, bh, acc[n], 0, 0, 0);
            }
        }
        if (more) {
#pragma unroll
            for (int i = 0; i < NPF; ++i) split_write(sb, soff[i], pf[i]);
        }
        __syncthreads();
    }

    // epilogue: logits(+bias) -> out score rows (scratch for K2)
#pragma unroll
    for (int n = 0; n < 2; ++n) {
        int e = e0 + wn * 32 + n * 16 + r;
        float bv = bias[e];
#pragma unroll
        for (int q = 0; q < 4; ++q) {
            int m = wt * 16 + g * 4 + q;
            out[(size_t)(tok0 + m) * EEXP + e] = acc[n][q] + bv;
        }
    }
}

// ---------------- Kernel 2 ----------------
#define NT2 256
#define TAU 2.5e-4f

__global__ __launch_bounds__(NT2) void router_select(
    const float* __restrict__ x, const float* __restrict__ w,
    const float* __restrict__ bias, float* __restrict__ out)
{
    __shared__ float  lrow[2][EEXP];
    __shared__ float  srow[2][EEXP];
    __shared__ float  cvf[2][8];
    __shared__ int    cie[2][8];
    __shared__ double cvd[2][8];
    __shared__ double sv4[2][4];
    __shared__ int    si4[2][4];
    __shared__ int    flg[2];

    const int tid = threadIdx.x;
    const int tg  = tid >> 7;           // token group 0/1
    const int e   = tid & 127;
    const int t   = blockIdx.x * 2 + tg;
    float* orow = out + (size_t)t * EEXP;

    float my = orow[e];                 // coalesced logit load
    lrow[tg][e] = my;
    srow[tg][e] = 0.f;
    __syncthreads();

    // parallel rank among 128 (strict total order, index tie-break)
    int rank = 0;
    const float4* lr4 = (const float4*)lrow[tg];
#pragma unroll 8
    for (int j4 = 0; j4 < EEXP / 4; ++j4) {
        float4 lv = lr4[j4];
        int jb = j4 * 4;
        rank += (lv.x > my) || (lv.x == my && (jb + 0) < e);
        rank += (lv.y > my) || (lv.y == my && (jb + 1) < e);
        rank += (lv.z > my) || (lv.z == my && (jb + 2) < e);
        rank += (lv.w > my) || (lv.w == my && (jb + 3) < e);
    }
    if (rank < 8) { cvf[tg][rank] = my; cie[tg][rank] = e; }
    __syncthreads();

    // certified-gap test on the 4 order-relevant gaps
    if (e == 0) {
        float gmin = 3.4e38f;
#pragma unroll
        for (int k = 0; k < 4; ++k)
            gmin = fminf(gmin, cvf[tg][k] - cvf[tg][k + 1]);
        flg[tg] = (gmin < TAU);
    }
    __syncthreads();
    const bool slow = (flg[tg] != 0);

    if (slow) {                          // rare: fp64 re-accumulation, 16 lanes/cand
        const int c = e >> 4, s = e & 15;
        const int ce = cie[tg][c];
        const float4* xr = (const float4*)(x + (size_t)t * HDIM);
        const float4* wr = (const float4*)(w + (size_t)ce * HDIM);
        double a0 = 0.0, a1 = 0.0, a2 = 0.0, a3 = 0.0;
        for (int i = 0; i < 45; ++i) {  // 45*16 = 720 float4
            int fi = s + i * 16;
            float4 xv = xr[fi];
            float4 wv = wr[fi];
            a0 = fma((double)xv.x, (double)wv.x, a0);
            a1 = fma((double)xv.y, (double)wv.y, a1);
            a2 = fma((double)xv.z, (double)wv.z, a2);
            a3 = fma((double)xv.w, (double)wv.w, a3);
        }
        double acc = (a0 + a2) + (a1 + a3);
#pragma unroll
        for (int off = 8; off > 0; off >>= 1)
            acc += __shfl_xor(acc, off); // closes within each 16-lane group
        if (s == 0) cvd[tg][c] = acc + (double)bias[ce];
    }
    __syncthreads();
    if (slow && e < 8) {                 // fp64 rank among the 8 candidates
        double mv = cvd[tg][e]; int mi = cie[tg][e];
        int rk = 0;
#pragma unroll
        for (int j2 = 0; j2 < 8; ++j2) {
            double oj = cvd[tg][j2];
            rk += (oj > mv) || (oj == mv && cie[tg][j2] < mi);
        }
        if (rk < 4) { sv4[tg][rk] = mv; si4[tg][rk] = mi; }
    }
    __syncthreads();

    if (e < 4) {
        float sc; int id;
        if (slow) {
            double m = sv4[tg][0];
            double s0 = exp(sv4[tg][0] - m), s1 = exp(sv4[tg][1] - m);
            double s2 = exp(sv4[tg][2] - m), s3 = exp(sv4[tg][3] - m);
            double ssum = ((s0 + s1) + (s2 + s3));
            double ek = exp(sv4[tg][e] - m);
            sc = (float)(ek / ssum); id = si4[tg][e];
        } else {
            float m = cvf[tg][0];
            float s0 = expf(cvf[tg][0] - m), s1 = expf(cvf[tg][1] - m);
            float s2 = expf(cvf[tg][2] - m), s3 = expf(cvf[tg][3] - m);
            float ssum = ((s0 + s1) + (s2 + s3));
            sc = expf(cvf[tg][e] - m) / ssum; id = cie[tg][e];
        }
        out[(size_t)T_TOK * EEXP + (size_t)t * KTOP + e] = (float)id;
        srow[tg][id] = sc;
    }
    __syncthreads();

    if (e < 32) ((float4*)orow)[e] = ((float4*)srow[tg])[e];
}

extern "C" void kernel_launch(void* const* d_in, const int* in_sizes, int n_in,
                              void* d_out, int out_size, void* d_ws, size_t ws_size,
                              hipStream_t stream) {
    const float* x    = (const float*)d_in[0];
    const float* w    = (const float*)d_in[1];
    const float* bias = (const float*)d_in[2];
    float* out        = (float*)d_out;

    hipLaunchKernelGGL(router_gemm, dim3((T_TOK / TM) * (EEXP / EN)), dim3(NT1),
                       0, stream, x, w, bias, out);
    hipLaunchKernelGGL(router_select, dim3(T_TOK / 2), dim3(NT2), 0, stream,
                       x, w, bias, out);
}